// Round 11
// baseline (12.513 us; speedup 1.0000x reference)
//
#include <hip/hip_runtime.h>
#include <math.h>

// SSKernelDiag: out[0,h,l] = 2*Re( sum_n C'[h,n] * A[h,n]^l )
//   A  = exp(al + i*ph),  C' = (C0 + i*C1)*(A-1)/(al + i*ph)
// H=256, N=64, L=4096, CH=1.
//
// Round 11: occupancy fix for the MFMA structure.
//   l = 64a + b;  K[a,b] = sum_n M[n,a]*G[n,b], M = 2C'*U^a (U=A^64), G = A^b.
//   Re(K) = Gr^T Mr - Gi^T Mi  ->  mfma_f32_16x16x32_f16.
// Grid 1024 = (head h, a-quad aq): block computes a in [16aq,16aq+16), all b.
// 4 blocks/CU x 4 waves = 4 waves/SIMD (R10 had 1: all latency exposed).
// Wave w owns output tile tb=w: 8 b128 fragment reads + 4 mfma + 1 store.
// Tables packed {f16 re, f16 im} per u32, row stride 76 u32 (R10-proven).

typedef _Float16       f16x8 __attribute__((ext_vector_type(8)));
typedef unsigned short u16x8 __attribute__((ext_vector_type(8)));
typedef unsigned int   u32x4 __attribute__((ext_vector_type(4)));
typedef float          f32x4 __attribute__((ext_vector_type(4)));

constexpr int H = 256;
constexpr int N = 64;
constexpr int L = 4096;
constexpr int STRIDE = 76;   // u32 words per table row (64 + 12 pad)

__global__ __launch_bounds__(256, 4)
void sskdiag_kernel(const float* __restrict__ A_abslog,
                    const float* __restrict__ A_phase,
                    const float* __restrict__ C,
                    float* __restrict__ out)
{
    __shared__ float4   s_t1[N];            // {al, phrev, Ar, Ai}
    __shared__ float4   s_t2[N];            // {Ur, Ui, 2C'r, 2C'i}
    __shared__ __align__(16) unsigned s_G[64 * STRIDE]; // row b: {f16 Gr, f16 -Gi}
    __shared__ __align__(16) unsigned s_M[16 * STRIDE]; // row j: {f16 Mr, f16  Mi}

    const int h   = blockIdx.x >> 2;
    const int aq  = blockIdx.x & 3;          // a = 16*aq + j, j in [0,16)
    const int tid = threadIdx.x;

    // ---- phase A: lane n computes per-n constants (one wave) ----
    if (tid < N) {
        const int n = tid;
        const float al = A_abslog[h * N + n];
        const float ph = A_phase [h * N + n];
        const double md = (double)ph * 0.15915494309189535;   // ph/(2*pi)
        const float phrev = (float)(md - floor(md));          // frac revolutions
        const float sp = __builtin_amdgcn_sinf(phrev);        // HW trig: revs
        const float cp = __builtin_amdgcn_cosf(phrev);
        const float m  = __expf(al);
        const float Ar = m * cp, Ai = m * sp;
        const float nr = Ar - 1.0f, ni = Ai;
        const float inv = 1.0f / (al * al + ph * ph);
        const float gr = (nr * al + ni * ph) * inv;
        const float gi = (ni * al - nr * ph) * inv;
        const float cre = C[(h * N + n) * 2 + 0];
        const float cim = C[(h * N + n) * 2 + 1];
        const float Cr = 2.0f * (cre * gr - cim * gi);        // fold the *2
        const float Ci = 2.0f * (cre * gi + cim * gr);
        // U = A^64 (angle from f64 md: exact reduction)
        const double m64 = 64.0 * md;
        const float f64a = (float)(m64 - floor(m64));
        const float mg64 = __expf(64.0f * al);
        s_t1[n] = make_float4(al, phrev, Ar, Ai);
        s_t2[n] = make_float4(mg64 * __builtin_amdgcn_cosf(f64a),
                              mg64 * __builtin_amdgcn_sinf(f64a), Cr, Ci);
    }
    __syncthreads();

    {
        const int n = tid & 63, q = tid >> 6;
        const float4 t1 = s_t1[n];
        const float4 t2 = s_t2[n];
        const float al = t1.x, phrev = t1.y;
        const float Ar = t1.z, Ai = t1.w;
        const float Ur = t2.x, Ui = t2.y;

        // ---- G fill: thread (n,q) seeds A^(16q), walks 16 rows (g *= A) ----
        {
            const float b0 = (float)(16 * q);
            float tg = phrev * b0;  tg -= floorf(tg);
            const float gmag = __expf(al * b0);
            float gre = gmag * __builtin_amdgcn_cosf(tg);
            float gim = gmag * __builtin_amdgcn_sinf(tg);
            #pragma unroll
            for (int k = 0; k < 16; ++k) {
                union { _Float16 hh[2]; unsigned u; } pg;
                pg.hh[0] = (_Float16)gre;  pg.hh[1] = (_Float16)(-gim);  // -Gi
                s_G[(16 * q + k) * STRIDE + n] = pg.u;  // stride-1 lanes: clean
                const float ngr = gre * Ar - gim * Ai;
                gim = gre * Ai + gim * Ar;  gre = ngr;
            }
        }
        // ---- M fill: rows j = 4q..4q+3; a = 16aq + j; exponent 64a on A ----
        {
            const float ebase = (float)(1024 * aq + 256 * q);
            float tm = phrev * ebase;  tm -= floorf(tm);
            const float umag = __expf(al * ebase);
            const float ure = umag * __builtin_amdgcn_cosf(tm);
            const float uim = umag * __builtin_amdgcn_sinf(tm);
            float mre = t2.z * ure - t2.w * uim;
            float mim = t2.z * uim + t2.w * ure;
            #pragma unroll
            for (int t = 0; t < 4; ++t) {
                union { _Float16 hh[2]; unsigned u; } pm;
                pm.hh[0] = (_Float16)mre;  pm.hh[1] = (_Float16)mim;
                s_M[(4 * q + t) * STRIDE + n] = pm.u;
                const float nmr = mre * Ur - mim * Ui;              // m *= U
                mim = mre * Ui + mim * Ur;  mre = nmr;
            }
        }
    }
    __syncthreads();

    // ---- wave w owns tile tb=w: read fragments (b128), 4 mfma, 1 store ----
    const int w    = tid >> 6;
    const int lane = tid & 63;
    const int e    = lane & 15;
    const int kg   = lane >> 4;

    f16x8 fGr[2], fGi[2], fMr[2], fMi[2];

    #pragma unroll
    for (int s = 0; s < 2; ++s) {
        {
            const unsigned* p = &s_G[(w * 16 + e) * STRIDE + 32 * s + 8 * kg];
            const u32x4 v0 = *reinterpret_cast<const u32x4*>(p);
            const u32x4 v1 = *reinterpret_cast<const u32x4*>(p + 4);
            u16x8 rr, ii;
            #pragma unroll
            for (int k = 0; k < 4; ++k) {
                rr[k]     = (unsigned short)(v0[k] & 0xffffu);
                ii[k]     = (unsigned short)(v0[k] >> 16);
                rr[k + 4] = (unsigned short)(v1[k] & 0xffffu);
                ii[k + 4] = (unsigned short)(v1[k] >> 16);
            }
            fGr[s] = __builtin_bit_cast(f16x8, rr);
            fGi[s] = __builtin_bit_cast(f16x8, ii);
        }
        {
            const unsigned* p = &s_M[e * STRIDE + 32 * s + 8 * kg];
            const u32x4 v0 = *reinterpret_cast<const u32x4*>(p);
            const u32x4 v1 = *reinterpret_cast<const u32x4*>(p + 4);
            u16x8 rr, ii;
            #pragma unroll
            for (int k = 0; k < 4; ++k) {
                rr[k]     = (unsigned short)(v0[k] & 0xffffu);
                ii[k]     = (unsigned short)(v0[k] >> 16);
                rr[k + 4] = (unsigned short)(v1[k] & 0xffffu);
                ii[k + 4] = (unsigned short)(v1[k] >> 16);
            }
            fMr[s] = __builtin_bit_cast(f16x8, rr);
            fMi[s] = __builtin_bit_cast(f16x8, ii);
        }
    }

    // Re = mfma(Gr,Mr) + mfma(-Gi,Mi), K accumulated over s
    f32x4 acc = {0.f, 0.f, 0.f, 0.f};
    #pragma unroll
    for (int s = 0; s < 2; ++s) {
        acc = __builtin_amdgcn_mfma_f32_16x16x32_f16(fGr[s], fMr[s], acc, 0, 0, 0);
        acc = __builtin_amdgcn_mfma_f32_16x16x32_f16(fGi[s], fMi[s], acc, 0, 0, 0);
    }

    // D[row=b][col=j]: b = w*16 + kg*4 + reg, a = 16*aq + e; l = 64a + b
    float4 v;
    v.x = acc[0];  v.y = acc[1];  v.z = acc[2];  v.w = acc[3];
    *reinterpret_cast<float4*>(out + h * L + (16 * aq + e) * 64 + w * 16 + kg * 4) = v;
}

extern "C" void kernel_launch(void* const* d_in, const int* in_sizes, int n_in,
                              void* d_out, int out_size, void* d_ws, size_t ws_size,
                              hipStream_t stream)
{
    const float* A_abslog = (const float*)d_in[0];
    const float* A_phase  = (const float*)d_in[1];
    const float* C        = (const float*)d_in[2];
    float* out = (float*)d_out;

    sskdiag_kernel<<<H * 4, 256, 0, stream>>>(A_abslog, A_phase, C, out);
}

// Round 12
// 10.969 us; speedup vs baseline: 1.1408x; 1.1408x over previous
//
#include <hip/hip_runtime.h>
#include <math.h>

// SSKernelDiag: out[0,h,l] = 2*Re( sum_n C'[h,n] * A[h,n]^l )
//   A  = exp(al + i*ph),  C' = (C0 + i*C1)*(A-1)/(al + i*ph)
// H=256, N=64, L=4096, CH=1.
//
// Round 12: R10 structure (grid=256, 1 head/block — best so far, 9.78us),
// same per-CU work, 3 fixes:
//   1) 512 threads = 8 waves = 2 waves/SIMD (R10: 1/SIMD, all latency bare)
//   2) fragment unpack via v_perm_b32: 8 ops/frag-pair (R10: ~32 shift/mask)
//   3) table-fill walk halved: thread (n, q in [0,8)) seeds row 8q, walks 8
// Tables (R10-proven layout): s_G[row b][n] = packed {f16 Gr, f16 -Gi} u32,
// s_M[row a][n] = {f16 Mr, f16 Mi}, row stride 76 u32. Wave w: ta = w>>1,
// tb in {2*(w&1), 2*(w&1)+1}; Re(K) = mfma(Gr,Mr) + mfma(-Gi,Mi).

typedef _Float16       f16x8 __attribute__((ext_vector_type(8)));
typedef unsigned int   u32x4 __attribute__((ext_vector_type(4)));
typedef float          f32x4 __attribute__((ext_vector_type(4)));

constexpr int H = 256;
constexpr int N = 64;
constexpr int L = 4096;
constexpr int STRIDE = 76;   // u32 words per table row (64 + 12 pad)

constexpr unsigned SEL_LO = 0x05040100u;  // {b.lo16, a.lo16}
constexpr unsigned SEL_HI = 0x07060302u;  // {b.hi16, a.hi16}

__global__ __launch_bounds__(512)
void sskdiag_kernel(const float* __restrict__ A_abslog,
                    const float* __restrict__ A_phase,
                    const float* __restrict__ C,
                    float* __restrict__ out)
{
    __shared__ float4   s_t1[N];            // {al, phrev, Ar, Ai}
    __shared__ float4   s_t2[N];            // {Ur, Ui, 2C'r, 2C'i}
    __shared__ __align__(16) unsigned s_G[64 * STRIDE]; // row b: {f16 Gr, f16 -Gi}
    __shared__ __align__(16) unsigned s_M[64 * STRIDE]; // row a: {f16 Mr, f16  Mi}

    const int h   = blockIdx.x;
    const int tid = threadIdx.x;

    // ---- phase A: lane n computes per-n constants (wave 0 only) ----
    if (tid < N) {
        const int n = tid;
        const float al = A_abslog[h * N + n];
        const float ph = A_phase [h * N + n];
        const double md = (double)ph * 0.15915494309189535;   // ph/(2*pi)
        const float phrev = (float)(md - floor(md));          // frac revolutions
        const float sp = __builtin_amdgcn_sinf(phrev);        // HW trig: revs
        const float cp = __builtin_amdgcn_cosf(phrev);
        const float m  = __expf(al);
        const float Ar = m * cp, Ai = m * sp;
        const float nr = Ar - 1.0f, ni = Ai;
        const float inv = 1.0f / (al * al + ph * ph);
        const float gr = (nr * al + ni * ph) * inv;
        const float gi = (ni * al - nr * ph) * inv;
        const float cre = C[(h * N + n) * 2 + 0];
        const float cim = C[(h * N + n) * 2 + 1];
        const float Cr = 2.0f * (cre * gr - cim * gi);        // fold the *2
        const float Ci = 2.0f * (cre * gi + cim * gr);
        // U = A^64 (angle from f64 md: exact reduction)
        const double m64 = 64.0 * md;
        const float f64a = (float)(m64 - floor(m64));
        const float mg64 = __expf(64.0f * al);
        s_t1[n] = make_float4(al, phrev, Ar, Ai);
        s_t2[n] = make_float4(mg64 * __builtin_amdgcn_cosf(f64a),
                              mg64 * __builtin_amdgcn_sinf(f64a), Cr, Ci);
    }
    __syncthreads();

    // ---- table fill: thread (n, q in [0,8)) seeds row 8q, walks 8 rows ----
    {
        const int n = tid & 63, q = tid >> 6;
        const float4 t1 = s_t1[n];
        const float4 t2 = s_t2[n];
        const float al = t1.x, phrev = t1.y;
        const float Ar = t1.z, Ai = t1.w;
        const float Ur = t2.x, Ui = t2.y;
        // G seed: A^(8q)
        const float b0 = (float)(8 * q);
        float tg = phrev * b0;  tg -= floorf(tg);
        const float gmag = __expf(al * b0);
        float gre = gmag * __builtin_amdgcn_cosf(tg);
        float gim = gmag * __builtin_amdgcn_sinf(tg);
        // M seed: 2C' * A^(512q)   (row a = 8q, exponent 64a)
        const float e0 = (float)(512 * q);
        float tm = phrev * e0;  tm -= floorf(tm);
        const float umag = __expf(al * e0);
        const float ure = umag * __builtin_amdgcn_cosf(tm);
        const float uim = umag * __builtin_amdgcn_sinf(tm);
        float mre = t2.z * ure - t2.w * uim;
        float mim = t2.z * uim + t2.w * ure;

        #pragma unroll
        for (int k = 0; k < 8; ++k) {
            const int row = 8 * q + k;
            union { _Float16 hh[2]; unsigned u; } pg, pm;
            pg.hh[0] = (_Float16)gre;  pg.hh[1] = (_Float16)(-gim);  // -Gi
            pm.hh[0] = (_Float16)mre;  pm.hh[1] = (_Float16)mim;
            s_G[row * STRIDE + n] = pg.u;   // lanes n stride-1: conflict-free
            s_M[row * STRIDE + n] = pm.u;
            const float ngr = gre * Ar - gim * Ai;              // g *= A
            gim = gre * Ai + gim * Ar;  gre = ngr;
            const float nmr = mre * Ur - mim * Ui;              // m *= U
            mim = mre * Ui + mim * Ur;  mre = nmr;
        }
    }
    __syncthreads();

    // ---- wave w: ta = w>>1, tb in {2*(w&1), 2*(w&1)+1} ----
    const int w    = tid >> 6;
    const int lane = tid & 63;
    const int e    = lane & 15;
    const int kg   = lane >> 4;
    const int ta   = w >> 1;
    const int tb0  = 2 * (w & 1);

    // M fragments (shared across both tb tiles)
    f16x8 fMr[2], fMi[2];
    #pragma unroll
    for (int s = 0; s < 2; ++s) {
        const unsigned* p = &s_M[(ta * 16 + e) * STRIDE + 32 * s + 8 * kg];
        const u32x4 v0 = *reinterpret_cast<const u32x4*>(p);
        const u32x4 v1 = *reinterpret_cast<const u32x4*>(p + 4);
        u32x4 rr, ii;
        rr[0] = __builtin_amdgcn_perm(v0[1], v0[0], SEL_LO);
        rr[1] = __builtin_amdgcn_perm(v0[3], v0[2], SEL_LO);
        rr[2] = __builtin_amdgcn_perm(v1[1], v1[0], SEL_LO);
        rr[3] = __builtin_amdgcn_perm(v1[3], v1[2], SEL_LO);
        ii[0] = __builtin_amdgcn_perm(v0[1], v0[0], SEL_HI);
        ii[1] = __builtin_amdgcn_perm(v0[3], v0[2], SEL_HI);
        ii[2] = __builtin_amdgcn_perm(v1[1], v1[0], SEL_HI);
        ii[3] = __builtin_amdgcn_perm(v1[3], v1[2], SEL_HI);
        fMr[s] = __builtin_bit_cast(f16x8, rr);
        fMi[s] = __builtin_bit_cast(f16x8, ii);
    }

    // Two output tiles per wave
    #pragma unroll
    for (int t = 0; t < 2; ++t) {
        const int tb = tb0 + t;
        f32x4 acc = {0.f, 0.f, 0.f, 0.f};
        #pragma unroll
        for (int s = 0; s < 2; ++s) {
            const unsigned* p = &s_G[(tb * 16 + e) * STRIDE + 32 * s + 8 * kg];
            const u32x4 v0 = *reinterpret_cast<const u32x4*>(p);
            const u32x4 v1 = *reinterpret_cast<const u32x4*>(p + 4);
            u32x4 rr, ii;
            rr[0] = __builtin_amdgcn_perm(v0[1], v0[0], SEL_LO);
            rr[1] = __builtin_amdgcn_perm(v0[3], v0[2], SEL_LO);
            rr[2] = __builtin_amdgcn_perm(v1[1], v1[0], SEL_LO);
            rr[3] = __builtin_amdgcn_perm(v1[3], v1[2], SEL_LO);
            ii[0] = __builtin_amdgcn_perm(v0[1], v0[0], SEL_HI);
            ii[1] = __builtin_amdgcn_perm(v0[3], v0[2], SEL_HI);
            ii[2] = __builtin_amdgcn_perm(v1[1], v1[0], SEL_HI);
            ii[3] = __builtin_amdgcn_perm(v1[3], v1[2], SEL_HI);
            const f16x8 fGr = __builtin_bit_cast(f16x8, rr);
            const f16x8 fGi = __builtin_bit_cast(f16x8, ii);
            acc = __builtin_amdgcn_mfma_f32_16x16x32_f16(fGr, fMr[s], acc, 0, 0, 0);
            acc = __builtin_amdgcn_mfma_f32_16x16x32_f16(fGi, fMi[s], acc, 0, 0, 0);
        }
        // D[row=b][col=a]: b = tb*16 + kg*4 + reg, a = ta*16 + e; l = 64a + b
        float4 v;
        v.x = acc[0];  v.y = acc[1];  v.z = acc[2];  v.w = acc[3];
        *reinterpret_cast<float4*>(out + h * L + (ta * 16 + e) * 64
                                   + tb * 16 + kg * 4) = v;
    }
}

extern "C" void kernel_launch(void* const* d_in, const int* in_sizes, int n_in,
                              void* d_out, int out_size, void* d_ws, size_t ws_size,
                              hipStream_t stream)
{
    const float* A_abslog = (const float*)d_in[0];
    const float* A_phase  = (const float*)d_in[1];
    const float* C        = (const float*)d_in[2];
    float* out = (float*)d_out;

    sskdiag_kernel<<<H, 512, 0, stream>>>(A_abslog, A_phase, C, out);
}